// Round 21
// baseline (349.322 us; speedup 1.0000x reference)
//
#include <hip/hip_runtime.h>
#include <hip/hip_bf16.h>

#define DEV_INLINE __device__ __forceinline__

typedef _Float16 f16;
typedef _Float16 f16x4 __attribute__((ext_vector_type(4)));
typedef _Float16 f16x8 __attribute__((ext_vector_type(8)));
typedef __bf16 bf16;
typedef __bf16 bf16x8 __attribute__((ext_vector_type(8)));
typedef float f32x16 __attribute__((ext_vector_type(16)));
typedef float f32x4 __attribute__((ext_vector_type(4)));

constexpr int N_NODES = 8192;
constexpr int G = 128;
constexpr int E_EDGES = 262144;

// ---------------------------------------------------------------------------
// Conv phase: operand-swapped MFMA (A=weights rows=channels, B=activations
// cols=positions). Act LDS: [node][parity][row][64ch*2B], row=halfpos+1,
// guard rows zeroed, 16B slots XOR-swizzled by row&7.
// ---------------------------------------------------------------------------
template<int MT, int LOG_PN, int IN_PS, int OUT_PS>
DEV_INLINE void conv_mid(const f16* __restrict__ wb, const float* __restrict__ bias,
                         char* inb, char* outb, int w, int l) {
  const int cht = w & 1;
  const int o_lane = cht * 32 + (l & 31);
  const int khalf = l >> 5;
  if ((w >> 1) < MT) {
    f16x8 wf[5][4];
#pragma unroll
    for (int k = 0; k < 5; k++)
#pragma unroll
      for (int s = 0; s < 4; s++)
        wf[k][s] = *(const f16x8*)&wb[(k * 64 + o_lane) * 64 + s * 16 + khalf * 8];
    f32x16 binit;
#pragma unroll
    for (int g = 0; g < 4; g++) {
      const float4 b4 = *(const float4*)&bias[cht * 32 + 8 * g + khalf * 4];
      binit[4 * g + 0] = b4.x; binit[4 * g + 1] = b4.y;
      binit[4 * g + 2] = b4.z; binit[4 * g + 3] = b4.w;
    }
    for (int mt = (w >> 1); mt < MT; mt += 2) {
      const int mo = mt * 32 + (l & 31);
      const int node = mo >> LOG_PN;
      const int po = mo & ((1 << LOG_PN) - 1);
      f32x16 acc = binit;
      f32x16 acc2 = {0,0,0,0,0,0,0,0,0,0,0,0,0,0,0,0};
#pragma unroll
      for (int k = 0; k < 5; k++) {
        const int d = k - 2;
        const int par = d & 1;
        const int row = po + (d >> 1) + 1;
        const char* rb = inb + ((node * 2 + par) * IN_PS + row) * 128;
        const int fx = row & 7;
#pragma unroll
        for (int s = 0; s < 4; s++) {
          const int c8 = 2 * s + khalf;
          f16x8 af = *(const f16x8*)(rb + ((c8 ^ fx) << 4));
          if (k & 1) acc2 = __builtin_amdgcn_mfma_f32_32x32x16_f16(wf[k][s], af, acc2, 0, 0, 0);
          else       acc  = __builtin_amdgcn_mfma_f32_32x32x16_f16(wf[k][s], af, acc, 0, 0, 0);
        }
      }
      const int orow = (po >> 1) + 1;
      const int ofx = orow & 7;
      char* base = outb + ((node * 2 + (po & 1)) * OUT_PS + orow) * 128 + khalf * 8;
#pragma unroll
      for (int g = 0; g < 4; g++) {
        f16x4 h4;
        h4[0] = (f16)fmaxf(acc[4 * g + 0] + acc2[4 * g + 0], 0.f);
        h4[1] = (f16)fmaxf(acc[4 * g + 1] + acc2[4 * g + 1], 0.f);
        h4[2] = (f16)fmaxf(acc[4 * g + 2] + acc2[4 * g + 2], 0.f);
        h4[3] = (f16)fmaxf(acc[4 * g + 3] + acc2[4 * g + 3], 0.f);
        *(f16x4*)(base + (((cht * 4 + g) ^ ofx) << 4)) = h4;
      }
    }
  }
}

// ---------------------------------------------------------------------------
// K_a: L1 + L2 (R12-verified); a2 out via LDS bounce -> coalesced stores
// ---------------------------------------------------------------------------
struct alignas(16) L12LDS {
  union {
    char act1[2][2][66][128];   // 33792
    char a2s[16384];
  } A;
  f16 xs16[2][272];
};                               // 34880 B -> 4 blocks/CU

__global__ __launch_bounds__(256, 4) void conv_l1l2_kernel(
    const float* __restrict__ x,
    const f16* __restrict__ w0f, const float* __restrict__ cb0,
    const f16* __restrict__ wbmid, const float* __restrict__ cb_mid,
    f16* __restrict__ a2g) {
  __shared__ L12LDS lds;
  const int tid = threadIdx.x;
  const int w = tid >> 6, l = tid & 63;
  const int n0 = blockIdx.x * 2;

  for (int idx = tid; idx < 512; idx += 256) {
    int node = idx >> 8, j = idx & 255;
    lds.xs16[node][3 + j] = (f16)x[(size_t)(n0 + node) * 256 + j];
  }
  if (tid < 64) {
    int node = tid >> 5, t = tid & 31;
    int par = (t >> 3) & 1, hi = t >> 4, j = t & 7;
    *(int4*)&lds.A.act1[node][par][hi ? 65 : 0][j * 16] = make_int4(0, 0, 0, 0);
  } else if (tid < 96) {
    int t3 = tid - 64;
    int node = t3 >> 4, s = t3 & 15;
    int slot = (s < 3) ? s : (256 + s);
    lds.xs16[node][slot] = (f16)0.f;
  }
  __syncthreads();

  // ---- L1 ----
  {
    const int cht = w & 1;
    const int o_lane = cht * 32 + (l & 31);
    const int khalf = l >> 5;
    const f16x8 w0frag = *(const f16x8*)&w0f[o_lane * 16 + khalf * 8];
    f32x16 binit;
#pragma unroll
    for (int g = 0; g < 4; g++) {
      const float4 b4 = *(const float4*)&cb0[cht * 32 + 8 * g + khalf * 4];
      binit[4 * g + 0] = b4.x; binit[4 * g + 1] = b4.y;
      binit[4 * g + 2] = b4.z; binit[4 * g + 3] = b4.w;
    }
    for (int mt = (w >> 1); mt < 8; mt += 2) {
      const int mo = mt * 32 + (l & 31);
      const int node = mo >> 7;
      const int po = mo & 127;
      union { uint u[4]; f16x8 v; } au;
      const char* ap = (const char*)&lds.xs16[node][2 * po + khalf * 8];
#pragma unroll
      for (int j = 0; j < 4; j++) au.u[j] = *(const uint*)(ap + 4 * j);
      f32x16 acc = __builtin_amdgcn_mfma_f32_32x32x16_f16(w0frag, au.v, binit, 0, 0, 0);
      const int orow = (po >> 1) + 1;
      const int ofx = orow & 7;
      char* base = (char*)lds.A.act1 + ((node * 2 + (po & 1)) * 66 + orow) * 128 + khalf * 8;
#pragma unroll
      for (int g = 0; g < 4; g++) {
        f16x4 h4;
        h4[0] = (f16)fmaxf(acc[4 * g + 0], 0.f);
        h4[1] = (f16)fmaxf(acc[4 * g + 1], 0.f);
        h4[2] = (f16)fmaxf(acc[4 * g + 2], 0.f);
        h4[3] = (f16)fmaxf(acc[4 * g + 3], 0.f);
        *(f16x4*)(base + (((cht * 4 + g) ^ ofx) << 4)) = h4;
      }
    }
  }
  __syncthreads();

  // ---- L2 -> LDS bounce -> coalesced a2g ----
  {
    const int cht = w & 1;
    const int o_lane = cht * 32 + (l & 31);
    const int khalf = l >> 5;
    f16x8 wf[5][4];
#pragma unroll
    for (int k = 0; k < 5; k++)
#pragma unroll
      for (int s = 0; s < 4; s++)
        wf[k][s] = *(const f16x8*)&wbmid[(k * 64 + o_lane) * 64 + s * 16 + khalf * 8];
    f32x16 binit;
#pragma unroll
    for (int g = 0; g < 4; g++) {
      const float4 b4 = *(const float4*)&cb_mid[cht * 32 + 8 * g + khalf * 4];
      binit[4 * g + 0] = b4.x; binit[4 * g + 1] = b4.y;
      binit[4 * g + 2] = b4.z; binit[4 * g + 3] = b4.w;
    }
    f16x4 outv[2][4];
#pragma unroll
    for (int it = 0; it < 2; it++) {
      const int mt = (w >> 1) + it * 2;
      const int mo = mt * 32 + (l & 31);
      const int node = mo >> 6;
      const int po = mo & 63;
      f32x16 acc = binit;
#pragma unroll
      for (int k = 0; k < 5; k++) {
        const int d = k - 2;
        const int par = d & 1;
        const int row = po + (d >> 1) + 1;
        const char* rb = (char*)lds.A.act1 + ((node * 2 + par) * 66 + row) * 128;
        const int fx = row & 7;
#pragma unroll
        for (int s = 0; s < 4; s++) {
          const int c8 = 2 * s + khalf;
          f16x8 af = *(const f16x8*)(rb + ((c8 ^ fx) << 4));
          acc = __builtin_amdgcn_mfma_f32_32x32x16_f16(wf[k][s], af, acc, 0, 0, 0);
        }
      }
#pragma unroll
      for (int g = 0; g < 4; g++) {
        outv[it][g][0] = (f16)fmaxf(acc[4 * g + 0], 0.f);
        outv[it][g][1] = (f16)fmaxf(acc[4 * g + 1], 0.f);
        outv[it][g][2] = (f16)fmaxf(acc[4 * g + 2], 0.f);
        outv[it][g][3] = (f16)fmaxf(acc[4 * g + 3], 0.f);
      }
    }
    __syncthreads();
#pragma unroll
    for (int it = 0; it < 2; it++) {
      const int mt = (w >> 1) + it * 2;
      const int row = mt * 32 + (l & 31);
      char* base = lds.A.a2s + row * 128 + khalf * 8;
#pragma unroll
      for (int g = 0; g < 4; g++)
        *(f16x4*)(base + (((cht * 4 + g) ^ (row & 7)) << 4)) = outv[it][g];
    }
    __syncthreads();
    char* gout = (char*)a2g + (size_t)n0 * 8192;
#pragma unroll
    for (int i = 0; i < 4; i++) {
      const int idx = tid + i * 256;
      const int row = idx >> 3, s = idx & 7;
      int4 v = *(const int4*)(lds.A.a2s + row * 128 + ((s ^ (row & 7)) << 4));
      *(int4*)(gout + idx * 16) = v;
    }
  }
}

// ---------------------------------------------------------------------------
// K_b: L3 + L4 + L5 + avg-pool + encoder — 4 nodes/block, LDS-aliased (R18).
// ---------------------------------------------------------------------------
struct alignas(16) L3LDS {
  union {
    char in2[4][2][34][128];       // 34816 (live: staging .. L3)
    struct {
      char act4[4][2][10][128];    // 10240 (live: L4 .. L5)
      float act5[32][68];          // 8704  (live: L5 .. pool)
      float pooled[4][256];        // 4096
      float encred[4][2][64];      // 2048
    } t;                            // 25088
  } U;
  char act3[4][2][18][128];        // 18432
};                                  // 53248 B -> 3 blocks/CU

__global__ __launch_bounds__(256, 3) void conv_l3tail_kernel(
    const f16* __restrict__ a2g,
    const f16* __restrict__ wbmid, const float* __restrict__ cb_mid,
    const f16* __restrict__ wb5, const float* __restrict__ cb_last,
    const f16* __restrict__ enc_w16, const float* __restrict__ enc_b,
    float* __restrict__ henc) {
  __shared__ L3LDS lds;
  const int tid = threadIdx.x;
  const int w = tid >> 6, l = tid & 63;
  const int n0 = blockIdx.x * 4;

#pragma unroll
  for (int i = 0; i < 8; i++) {
    const int idx = tid + i * 256;
    const int node = idx >> 9;
    const int rem = idx & 511;
    const int p = rem >> 3, s8 = rem & 7;
    const int row = (p >> 1) + 1, par = p & 1;
    int4 v = *(const int4*)&a2g[((size_t)(n0 + node) * 64 + p) * 64 + s8 * 8];
    *(int4*)((char*)lds.U.in2 + ((node * 2 + par) * 34 + row) * 128
             + ((s8 ^ (row & 7)) << 4)) = v;
  }
  for (int gg = tid; gg < 256; gg += 256) {
    int which = gg >> 7;
    int t = gg & 127;
    int node = t >> 5, tt = t & 31;
    int par = (tt >> 3) & 1, hi = tt >> 4, j = tt & 7;
    if (which == 0)
      *(int4*)&lds.U.in2[node][par][hi ? 33 : 0][j * 16] = make_int4(0, 0, 0, 0);
    else
      *(int4*)&lds.act3[node][par][hi ? 17 : 0][j * 16] = make_int4(0, 0, 0, 0);
  }
  __syncthreads();

  conv_mid<4, 5, 34, 18>(wbmid + 5 * 64 * 64, cb_mid + 64,
                         (char*)lds.U.in2, (char*)lds.act3, w, l);
  __syncthreads();

  if (tid < 128) {
    int node = tid >> 5, tt = tid & 31;
    int par = (tt >> 3) & 1, hi = tt >> 4, j = tt & 7;
    *(int4*)&lds.U.t.act4[node][par][hi ? 9 : 0][j * 16] = make_int4(0, 0, 0, 0);
  }
  conv_mid<2, 4, 18, 10>(wbmid + 2 * 5 * 64 * 64, cb_mid + 128,
                         (char*)lds.act3, (char*)lds.U.t.act4, w, l);
  __syncthreads();

  {
    const int ch_row = w * 16 + (l & 15);
    const int kq = l >> 4;
    f16x8 wf5[3][2];
#pragma unroll
    for (int k = 0; k < 3; k++)
#pragma unroll
      for (int s = 0; s < 2; s++)
        wf5[k][s] = *(const f16x8*)&wb5[(k * 64 + ch_row) * 64 + s * 32 + kq * 8];
    const float4 b4 = *(const float4*)&cb_last[w * 16 + kq * 4];
#pragma unroll
    for (int pt = 0; pt < 2; pt++) {
      f32x4 acc5 = {b4.x, b4.y, b4.z, b4.w};
      const int pos = pt * 16 + (l & 15);
      const int nd5 = pos >> 3, p5 = pos & 7;
#pragma unroll
      for (int k = 0; k < 3; k++) {
        const int d = k - 1;
        const int par = d & 1;
        const int row = p5 + (d >> 1) + 1;
        const char* rb = (char*)lds.U.t.act4 + ((nd5 * 2 + par) * 10 + row) * 128;
        const int fx = row & 7;
#pragma unroll
        for (int s = 0; s < 2; s++) {
          const int c8 = 4 * s + kq;
          f16x8 af = *(const f16x8*)(rb + ((c8 ^ fx) << 4));
          acc5 = __builtin_amdgcn_mfma_f32_16x16x32_f16(wf5[k][s], af, acc5, 0, 0, 0);
        }
      }
      f32x4 o4;
      o4[0] = fmaxf(acc5[0], 0.f);
      o4[1] = fmaxf(acc5[1], 0.f);
      o4[2] = fmaxf(acc5[2], 0.f);
      o4[3] = fmaxf(acc5[3], 0.f);
      *(f32x4*)&lds.U.t.act5[pos][w * 16 + kq * 4] = o4;
    }
  }
  __syncthreads();

  for (int jj = tid; jj < 1024; jj += 256) {
    int node = jj >> 8, j = jj & 255;
    int c = j >> 2, q = j & 3;
    const float* a5 = &lds.U.t.act5[node * 8][0];
    float v = a5[(2 * q) * 68 + c] + a5[(2 * q + 1) * 68 + c];
    if (q > 0) v += a5[(2 * q - 1) * 68 + c];
    lds.U.t.pooled[node][j] = v * (1.f / 3.f);
  }
  __syncthreads();

  for (int nn = 0; nn < 4; nn += 2) {
    const int node = nn + (tid >> 7);
    const int tt = tid & 127;
    const int o = tt & 63, jg = tt >> 6;
    float acc = 0.f;
    const f16x8* ew = (const f16x8*)&enc_w16[o * 256 + jg * 128];
    const float4* pj = (const float4*)&lds.U.t.pooled[node][jg * 128];
#pragma unroll 4
    for (int j8 = 0; j8 < 16; j8++) {
      f16x8 e8 = ew[j8];
      float4 p0 = pj[2 * j8], p1 = pj[2 * j8 + 1];
      acc += (float)e8[0] * p0.x + (float)e8[1] * p0.y +
             (float)e8[2] * p0.z + (float)e8[3] * p0.w +
             (float)e8[4] * p1.x + (float)e8[5] * p1.y +
             (float)e8[6] * p1.z + (float)e8[7] * p1.w;
    }
    lds.U.t.encred[node][jg][o] = acc;
  }
  __syncthreads();
  {
    int node = tid >> 6, o = tid & 63;
    henc[(size_t)(n0 + node) * 64 + o] =
        lds.U.t.encred[node][0][o] + lds.U.t.encred[node][1][o] + enc_b[o];
  }
}

// ---------------------------------------------------------------------------
// merged weight prep: conv f16 + enc f16 + GNN bf16 hi/lo
// ---------------------------------------------------------------------------
__global__ void wprep_all(const float* __restrict__ cw0,
                          const float* __restrict__ cw_mid, const float* __restrict__ cw_last,
                          const float* __restrict__ enc_w,
                          const float* __restrict__ g0_rel, const float* __restrict__ g0_root,
                          const float* __restrict__ g0_rel_b,
                          const float* __restrict__ g_rel, const float* __restrict__ g_root,
                          const float* __restrict__ g_rel_b,
                          f16* __restrict__ w0f, f16* __restrict__ wbmid, f16* __restrict__ wb5,
                          f16* __restrict__ enc_w16,
                          bf16* __restrict__ wg, float* __restrict__ bg) {
  int idx = blockIdx.x * 256 + threadIdx.x;
  if (idx < 64 * 16) {
    int o = idx >> 4, k = idx & 15;
    w0f[idx] = (k < 7) ? (f16)cw0[o * 7 + k] : (f16)0.f;
  }
  if (idx < 3 * 5 * 64 * 64) {
    int lay = idx / (5 * 64 * 64);
    int rem = idx % (5 * 64 * 64);
    int k = rem / 4096;
    int o = (rem >> 6) & 63;
    int c = rem & 63;
    wbmid[idx] = (f16)cw_mid[((lay * 64 + o) * 64 + c) * 5 + k];
  } else {
    int i2 = idx - 3 * 5 * 64 * 64;
    if (i2 < 3 * 64 * 64) {
      int k = i2 / 4096;
      int o = (i2 >> 6) & 63;
      int c = i2 & 63;
      wb5[i2] = (f16)cw_last[(o * 64 + c) * 3 + k];
    }
  }
  if (idx < 64 * 256) enc_w16[idx] = (f16)enc_w[idx];
  if (idx < 128 * 128) {
    int o = idx >> 7, k = idx & 127;
    float v = (k < 64) ? g0_rel[o * 64 + k] : g0_root[o * 64 + (k - 64)];
    bf16 h = (bf16)v;
    wg[idx] = h;
    wg[128 * 128 + idx] = (bf16)(v - (float)h);
  }
  if (idx < 7 * 128 * 256) {
    int lsel = idx / (128 * 256);
    int r = idx % (128 * 256);
    int o = r >> 8, k = r & 255;
    float v = (k < 128) ? g_rel[(lsel * 128 + o) * 128 + k]
                        : g_root[(lsel * 128 + o) * 128 + (k - 128)];
    bf16 h = (bf16)v;
    size_t base = 2 * 128 * 128 + (size_t)lsel * 2 * 128 * 256;
    wg[base + r] = h;
    wg[base + 128 * 256 + r] = (bf16)(v - (float)h);
  }
  if (idx < 8 * 128) {
    int lsel = idx >> 7, o = idx & 127;
    bg[idx] = (lsel == 0) ? g0_rel_b[o] : g_rel_b[(lsel - 1) * 128 + o];
  }
}

// ---------------------------------------------------------------------------
// CSR build
// ---------------------------------------------------------------------------
__global__ void hist_kernel(const int* __restrict__ dst, int* __restrict__ cnt) {
  int e = blockIdx.x * 256 + threadIdx.x;
  atomicAdd(&cnt[dst[e]], 1);
}

__global__ void scan_kernel(const int* __restrict__ cnt, int* __restrict__ rp) {
  __shared__ int part[256];
  int t = threadIdx.x;
  int base = t * 32;
  int local[32];
  int s = 0;
#pragma unroll
  for (int i = 0; i < 32; i++) { local[i] = cnt[base + i]; s += local[i]; }
  part[t] = s;
  __syncthreads();
  for (int off = 1; off < 256; off <<= 1) {
    int v = (t >= off) ? part[t - off] : 0;
    __syncthreads();
    part[t] += v;
    __syncthreads();
  }
  int run = part[t] - s;
#pragma unroll
  for (int i = 0; i < 32; i++) { rp[base + i] = run; run += local[i]; }
  if (t == 255) rp[N_NODES] = run;
}

__global__ void fill_kernel(const int* __restrict__ src, const int* __restrict__ dst,
                            const int* __restrict__ rp, int* __restrict__ cur,
                            int* __restrict__ csr) {
  int e = blockIdx.x * 256 + threadIdx.x;
  int r = dst[e];
  int p = atomicAdd(&cur[r], 1);
  csr[rp[r] + p] = src[e];
}

// ---------------------------------------------------------------------------
// f32 gather, 4-group neighbor split (chain = 2 batches). Per group: R18's
// 4-deep float4 body, stride 4. D=64: all groups in one wave, shfl-only
// combine. D=128: 2 waves/node; intra-wave shfl + LDS cross-wave combine.
// ---------------------------------------------------------------------------
template<int D>
__global__ __launch_bounds__(256) void gatherf(
    const float* __restrict__ h, const int* __restrict__ csr,
    const int* __restrict__ rp, float* __restrict__ agg) {
  constexpr int LPN = D / 4;            // lanes per group (32 or 16)
  constexpr int TPN = 4 * LPN;          // threads per node (128 or 64)
  constexpr int NPB = 256 / TPN;        // nodes per block (2 or 4)
  __shared__ float4 part[NPB][LPN];
  const int nloc = threadIdx.x / TPN;
  const int node = blockIdx.x * NPB + nloc;
  const int grp = (threadIdx.x / LPN) & 3;
  const int cl = threadIdx.x & (LPN - 1);
  const int s = rp[node], e = rp[node + 1];
  float4 a0 = make_float4(0.f, 0.f, 0.f, 0.f);
  float4 a1 = make_float4(0.f, 0.f, 0.f, 0.f);
  float4 a2 = make_float4(0.f, 0.f, 0.f, 0.f);
  float4 a3 = make_float4(0.f, 0.f, 0.f, 0.f);
  int i = s + grp;
  for (; i + 12 < e; i += 16) {
    const int m0 = csr[i], m1 = csr[i + 4], m2 = csr[i + 8], m3 = csr[i + 12];
    float4 v0 = *(const float4*)&h[(size_t)m0 * D + cl * 4];
    float4 v1 = *(const float4*)&h[(size_t)m1 * D + cl * 4];
    float4 v2 = *(const float4*)&h[(size_t)m2 * D + cl * 4];
    float4 v3 = *(const float4*)&h[(size_t)m3 * D + cl * 4];
    a0.x += v0.x; a0.y += v0.y; a0.z += v0.z; a0.w += v0.w;
    a1.x += v1.x; a1.y += v1.y; a1.z += v1.z; a1.w += v1.w;
    a2.x += v2.x; a2.y += v2.y; a2.z += v2.z; a2.w += v2.w;
    a3.x += v3.x; a3.y += v3.y; a3.z += v3.z; a3.w += v3.w;
  }
  for (; i < e; i += 4) {
    const int m0 = csr[i];
    float4 v0 = *(const float4*)&h[(size_t)m0 * D + cl * 4];
    a0.x += v0.x; a0.y += v0.y; a0.z += v0.z; a0.w += v0.w;
  }
  float4 r0;
  r0.x = (a0.x + a1.x) + (a2.x + a3.x);
  r0.y = (a0.y + a1.y) + (a2.y + a3.y);
  r0.z = (a0.z + a1.z) + (a2.z + a3.z);
  r0.w = (a0.w + a1.w) + (a2.w + a3.w);
  if (D == 64) {
    // all 4 groups in one wave: combine with two shfl steps
    r0.x += __shfl_xor(r0.x, LPN);
    r0.y += __shfl_xor(r0.y, LPN);
    r0.z += __shfl_xor(r0.z, LPN);
    r0.w += __shfl_xor(r0.w, LPN);
    r0.x += __shfl_xor(r0.x, 2 * LPN);
    r0.y += __shfl_xor(r0.y, 2 * LPN);
    r0.z += __shfl_xor(r0.z, 2 * LPN);
    r0.w += __shfl_xor(r0.w, 2 * LPN);
    if (grp == 0)
      *(float4*)&agg[(size_t)node * D + cl * 4] = r0;
  } else {
    // groups 0,1 in wave A; groups 2,3 in wave B. intra-wave pair combine:
    r0.x += __shfl_xor(r0.x, LPN);
    r0.y += __shfl_xor(r0.y, LPN);
    r0.z += __shfl_xor(r0.z, LPN);
    r0.w += __shfl_xor(r0.w, LPN);
    if (grp == 2) part[nloc][cl] = r0;   // wave B's partial (grps 2+3)
    __syncthreads();
    if (grp == 0) {
      float4 p = part[nloc][cl];
      r0.x += p.x; r0.y += p.y; r0.z += p.z; r0.w += p.w;
      *(float4*)&agg[(size_t)node * D + cl * 4] = r0;
    }
  }
}

// ---------------------------------------------------------------------------
// GNN layer GEMM, bf16 hi/lo split both operands. 32 nodes/block. (R12)
// ---------------------------------------------------------------------------
template<int K>
__global__ __launch_bounds__(256) void gnn_gemm_bf(
    const float* __restrict__ agg, const float* __restrict__ hroot,
    const bf16* __restrict__ wg, const float* __restrict__ bg,
    float* __restrict__ hout) {
  constexpr int F = K / 2;
  constexpr int ROWB = K * 2;
  constexpr int KSTEPS = K / 16;
  __shared__ alignas(16) char smem[2][32 * K * 2];
  const int tid = threadIdx.x;
  const int l = tid & 63, w = tid >> 6;
  const int n0 = blockIdx.x * 32;

  {
    const int row = tid >> 3, p = tid & 7;
    constexpr int cpp = K / 64;
#pragma unroll
    for (int j = 0; j < cpp; j++) {
      const int slot = p * cpp + j;
      const int c0 = slot * 8;
      const float* src = (c0 < F) ? &agg[(size_t)(n0 + row) * F + c0]
                                  : &hroot[(size_t)(n0 + row) * F + (c0 - F)];
      float4 v0 = ((const float4*)src)[0];
      float4 v1 = ((const float4*)src)[1];
      float vv[8] = {v0.x, v0.y, v0.z, v0.w, v1.x, v1.y, v1.z, v1.w};
      bf16x8 hi8, lo8;
#pragma unroll
      for (int e = 0; e < 8; e++) {
        float v = vv[e];
        bf16 h = (bf16)v;
        hi8[e] = h;
        lo8[e] = (bf16)(v - (float)h);
      }
      const int off = row * ROWB + ((slot ^ (row & 7)) << 4);
      *(bf16x8*)(smem[0] + off) = hi8;
      *(bf16x8*)(smem[1] + off) = lo8;
    }
  }

  const int ch = w * 32 + (l & 31);
  const int khalf = l >> 5;
  bf16x8 whi[KSTEPS], wlo[KSTEPS];
  const bf16* wrow = wg + (size_t)ch * K + khalf * 8;
#pragma unroll
  for (int ks = 0; ks < KSTEPS; ks++) {
    whi[ks] = *(const bf16x8*)&wrow[ks * 16];
    wlo[ks] = *(const bf16x8*)&wrow[128 * K + ks * 16];
  }
  const float bv = bg[ch];

  __syncthreads();

  const int row0 = l & 31;
  f32x16 acc = {0,0,0,0,0,0,0,0,0,0,0,0,0,0,0,0};
#pragma unroll
  for (int ks = 0; ks < KSTEPS; ks++) {
    const int slot = ks * 2 + khalf;
    const int off = row0 * ROWB + ((slot ^ (row0 & 7)) << 4);
    bf16x8 ah = *(const bf16x8*)(smem[0] + off);
    bf16x8 al = *(const bf16x8*)(smem[1] + off);
    acc = __builtin_amdgcn_mfma_f32_32x32x16_bf16(ah, whi[ks], acc, 0, 0, 0);
    acc = __builtin_amdgcn_mfma_f32_32x32x16_bf16(al, whi[ks], acc, 0, 0, 0);
    acc = __builtin_amdgcn_mfma_f32_32x32x16_bf16(ah, wlo[ks], acc, 0, 0, 0);
  }

#pragma unroll
  for (int r = 0; r < 16; r++) {
    const int nl = (r & 3) + 8 * (r >> 2) + 4 * khalf;
    hout[(size_t)(n0 + nl) * 128 + ch] = fmaxf(acc[r] + bv, 0.f);
  }
}

// ---------------------------------------------------------------------------
// graph mean-pool (block per graph, no atomics) + MLP head
// ---------------------------------------------------------------------------
__global__ __launch_bounds__(256) void poolg(const float* __restrict__ h,
                                             float* __restrict__ pooled) {
  const int g = blockIdx.x;
  const int tid = threadIdx.x;
  const int ch = tid & 127, half = tid >> 7;
  const float* base = h + ((size_t)g * 64 + half * 32) * 128 + ch;
  float s = 0.f;
#pragma unroll 8
  for (int i = 0; i < 32; i++) s += base[(size_t)i * 128];
  __shared__ float red[256];
  red[tid] = s;
  __syncthreads();
  if (tid < 128) pooled[(size_t)g * 128 + tid] = (red[tid] + red[tid + 128]) * (1.f / 64.f);
}

__global__ __launch_bounds__(128) void mlp_kernel(
    const float* __restrict__ pooled,
    const float* __restrict__ lin_w, const float* __restrict__ lin_b,
    const float* __restrict__ out_w, const float* __restrict__ out_b,
    float* __restrict__ out) {
  const int g = blockIdx.x;
  const int t = threadIdx.x;
  __shared__ float hs[128];
  __shared__ float lg[2];
  hs[t] = pooled[(size_t)g * 128 + t];
  __syncthreads();
  for (int lsel = 0; lsel < 3; lsel++) {
    float acc = lin_b[lsel * 128 + t];
    for (int j = 0; j < 128; j++) acc += hs[j] * lin_w[(lsel * 128 + t) * 128 + j];
    __syncthreads();
    hs[t] = fmaxf(acc, 0.f);
    __syncthreads();
  }
  if (t < 2) {
    float acc = out_b[t];
    for (int j = 0; j < 128; j++) acc += hs[j] * out_w[t * 128 + j];
    lg[t] = acc;
  }
  __syncthreads();
  if (t < 2) {
    float m = fmaxf(lg[0], lg[1]);
    float lse = m + logf(expf(lg[0] - m) + expf(lg[1] - m));
    out[g * 2 + t] = lg[t] - lse;
  }
}

// ---------------------------------------------------------------------------
extern "C" void kernel_launch(void* const* d_in, const int* in_sizes, int n_in,
                              void* d_out, int out_size, void* d_ws, size_t ws_size,
                              hipStream_t stream) {
  const float* x       = (const float*)d_in[0];
  const int*   edge    = (const int*)d_in[1];
  const float* cw0     = (const float*)d_in[3];
  const float* cb0     = (const float*)d_in[4];
  const float* cw_mid  = (const float*)d_in[5];
  const float* cb_mid  = (const float*)d_in[6];
  const float* cw_last = (const float*)d_in[7];
  const float* cb_last = (const float*)d_in[8];
  const float* enc_w   = (const float*)d_in[9];
  const float* enc_b   = (const float*)d_in[10];
  const float* g0_rel_w  = (const float*)d_in[11];
  const float* g0_rel_b  = (const float*)d_in[12];
  const float* g0_root_w = (const float*)d_in[13];
  const float* g_rel_w   = (const float*)d_in[14];
  const float* g_rel_b   = (const float*)d_in[15];
  const float* g_root_w  = (const float*)d_in[16];
  const float* lin_w     = (const float*)d_in[17];
  const float* lin_b     = (const float*)d_in[18];
  const float* out_w     = (const float*)d_in[19];
  const float* out_b     = (const float*)d_in[20];
  float* out = (float*)d_out;

  const int* esrc = edge;
  const int* edst = edge + E_EDGES;

  char* ws = (char*)d_ws;
  size_t off = 0;
  auto alloc = [&](size_t bytes) {
    void* p = ws + off;
    off += (bytes + 255) & ~size_t(255);
    return p;
  };
  float* henc = (float*)alloc((size_t)N_NODES * 64 * 4);
  float* hA   = (float*)alloc((size_t)N_NODES * 128 * 4);
  float* hB   = (float*)alloc((size_t)N_NODES * 128 * 4);
  float* agg  = (float*)alloc((size_t)N_NODES * 128 * 4);
  bf16* wg    = (bf16*)alloc((size_t)(128 * 128 + 7 * 128 * 256) * 2 * 2);
  float* bg   = (float*)alloc((size_t)8 * 128 * 4);
  float* pooled = (float*)alloc((size_t)G * 128 * 4);
  int* cnt  = (int*)alloc((size_t)N_NODES * 4);
  int* rp   = (int*)alloc((size_t)(N_NODES + 1) * 4);
  int* cur  = (int*)alloc((size_t)N_NODES * 4);
  int* csr  = (int*)alloc((size_t)E_EDGES * 4);
  f16* w0f   = (f16*)alloc((size_t)64 * 16 * 2);
  f16* wbmid = (f16*)alloc((size_t)3 * 5 * 64 * 64 * 2);
  f16* wb5   = (f16*)alloc((size_t)3 * 64 * 64 * 2);
  f16* enc_w16 = (f16*)alloc((size_t)64 * 256 * 2);
  f16* a2g   = (f16*)alloc((size_t)N_NODES * 64 * 64 * 2);   // 67 MB

  hipMemsetAsync(cnt, 0, (size_t)N_NODES * 4, stream);
  hipMemsetAsync(cur, 0, (size_t)N_NODES * 4, stream);

  wprep_all<<<896, 256, 0, stream>>>(cw0, cw_mid, cw_last, enc_w,
                                     g0_rel_w, g0_root_w, g0_rel_b,
                                     g_rel_w, g_root_w, g_rel_b,
                                     w0f, wbmid, wb5, enc_w16, wg, bg);
  conv_l1l2_kernel<<<N_NODES / 2, 256, 0, stream>>>(x, w0f, cb0, wbmid, cb_mid, a2g);
  conv_l3tail_kernel<<<N_NODES / 4, 256, 0, stream>>>(
      a2g, wbmid, cb_mid, wb5, cb_last, enc_w16, enc_b, henc);

  hist_kernel<<<E_EDGES / 256, 256, 0, stream>>>(edst, cnt);
  scan_kernel<<<1, 256, 0, stream>>>(cnt, rp);
  fill_kernel<<<E_EDGES / 256, 256, 0, stream>>>(esrc, edst, rp, cur, csr);

  // layer 0 (K=128: 64 agg + 64 root); D=64 -> 64 thr/node, 4 nodes/block
  gatherf<64><<<N_NODES / 4, 256, 0, stream>>>(henc, csr, rp, agg);
  gnn_gemm_bf<128><<<N_NODES / 32, 256, 0, stream>>>(agg, henc, wg, bg, hA);

  float* hprev = hA;
  float* hnext = hB;
  for (int lsel = 0; lsel < 7; lsel++) {
    // D=128 -> 128 thr/node, 2 nodes/block
    gatherf<128><<<N_NODES / 2, 256, 0, stream>>>(hprev, csr, rp, agg);
    gnn_gemm_bf<256><<<N_NODES / 32, 256, 0, stream>>>(
        agg, hprev, wg + 2 * 128 * 128 + (size_t)lsel * 2 * 128 * 256,
        bg + (lsel + 1) * 128, hnext);
    float* tmp = hprev; hprev = hnext; hnext = tmp;
  }

  poolg<<<G, 256, 0, stream>>>(hprev, pooled);
  mlp_kernel<<<G, 128, 0, stream>>>(pooled, lin_w, lin_b, out_w, out_b, out);
}

// Round 22
// 340.616 us; speedup vs baseline: 1.0256x; 1.0256x over previous
//
#include <hip/hip_runtime.h>
#include <hip/hip_bf16.h>

#define DEV_INLINE __device__ __forceinline__

typedef _Float16 f16;
typedef _Float16 f16x4 __attribute__((ext_vector_type(4)));
typedef _Float16 f16x8 __attribute__((ext_vector_type(8)));
typedef __bf16 bf16;
typedef __bf16 bf16x8 __attribute__((ext_vector_type(8)));
typedef float f32x16 __attribute__((ext_vector_type(16)));
typedef float f32x4 __attribute__((ext_vector_type(4)));

constexpr int N_NODES = 8192;
constexpr int G = 128;
constexpr int E_EDGES = 262144;

// ---------------------------------------------------------------------------
// Conv phase: operand-swapped MFMA (A=weights rows=channels, B=activations
// cols=positions). Act LDS: [node][parity][row][64ch*2B], row=halfpos+1,
// guard rows zeroed, 16B slots XOR-swizzled by row&7.
// ---------------------------------------------------------------------------
template<int MT, int LOG_PN, int IN_PS, int OUT_PS>
DEV_INLINE void conv_mid(const f16* __restrict__ wb, const float* __restrict__ bias,
                         char* inb, char* outb, int w, int l) {
  const int cht = w & 1;
  const int o_lane = cht * 32 + (l & 31);
  const int khalf = l >> 5;
  if ((w >> 1) < MT) {
    f16x8 wf[5][4];
#pragma unroll
    for (int k = 0; k < 5; k++)
#pragma unroll
      for (int s = 0; s < 4; s++)
        wf[k][s] = *(const f16x8*)&wb[(k * 64 + o_lane) * 64 + s * 16 + khalf * 8];
    f32x16 binit;
#pragma unroll
    for (int g = 0; g < 4; g++) {
      const float4 b4 = *(const float4*)&bias[cht * 32 + 8 * g + khalf * 4];
      binit[4 * g + 0] = b4.x; binit[4 * g + 1] = b4.y;
      binit[4 * g + 2] = b4.z; binit[4 * g + 3] = b4.w;
    }
    for (int mt = (w >> 1); mt < MT; mt += 2) {
      const int mo = mt * 32 + (l & 31);
      const int node = mo >> LOG_PN;
      const int po = mo & ((1 << LOG_PN) - 1);
      f32x16 acc = binit;
      f32x16 acc2 = {0,0,0,0,0,0,0,0,0,0,0,0,0,0,0,0};
#pragma unroll
      for (int k = 0; k < 5; k++) {
        const int d = k - 2;
        const int par = d & 1;
        const int row = po + (d >> 1) + 1;
        const char* rb = inb + ((node * 2 + par) * IN_PS + row) * 128;
        const int fx = row & 7;
#pragma unroll
        for (int s = 0; s < 4; s++) {
          const int c8 = 2 * s + khalf;
          f16x8 af = *(const f16x8*)(rb + ((c8 ^ fx) << 4));
          if (k & 1) acc2 = __builtin_amdgcn_mfma_f32_32x32x16_f16(wf[k][s], af, acc2, 0, 0, 0);
          else       acc  = __builtin_amdgcn_mfma_f32_32x32x16_f16(wf[k][s], af, acc, 0, 0, 0);
        }
      }
      const int orow = (po >> 1) + 1;
      const int ofx = orow & 7;
      char* base = outb + ((node * 2 + (po & 1)) * OUT_PS + orow) * 128 + khalf * 8;
#pragma unroll
      for (int g = 0; g < 4; g++) {
        f16x4 h4;
        h4[0] = (f16)fmaxf(acc[4 * g + 0] + acc2[4 * g + 0], 0.f);
        h4[1] = (f16)fmaxf(acc[4 * g + 1] + acc2[4 * g + 1], 0.f);
        h4[2] = (f16)fmaxf(acc[4 * g + 2] + acc2[4 * g + 2], 0.f);
        h4[3] = (f16)fmaxf(acc[4 * g + 3] + acc2[4 * g + 3], 0.f);
        *(f16x4*)(base + (((cht * 4 + g) ^ ofx) << 4)) = h4;
      }
    }
  }
}

// ---------------------------------------------------------------------------
// K_a: L1 + L2 (R12-verified); a2 out via LDS bounce -> coalesced stores
// ---------------------------------------------------------------------------
struct alignas(16) L12LDS {
  union {
    char act1[2][2][66][128];   // 33792
    char a2s[16384];
  } A;
  f16 xs16[2][272];
};                               // 34880 B -> 4 blocks/CU

__global__ __launch_bounds__(256, 4) void conv_l1l2_kernel(
    const float* __restrict__ x,
    const f16* __restrict__ w0f, const float* __restrict__ cb0,
    const f16* __restrict__ wbmid, const float* __restrict__ cb_mid,
    f16* __restrict__ a2g) {
  __shared__ L12LDS lds;
  const int tid = threadIdx.x;
  const int w = tid >> 6, l = tid & 63;
  const int n0 = blockIdx.x * 2;

  for (int idx = tid; idx < 512; idx += 256) {
    int node = idx >> 8, j = idx & 255;
    lds.xs16[node][3 + j] = (f16)x[(size_t)(n0 + node) * 256 + j];
  }
  if (tid < 64) {
    int node = tid >> 5, t = tid & 31;
    int par = (t >> 3) & 1, hi = t >> 4, j = t & 7;
    *(int4*)&lds.A.act1[node][par][hi ? 65 : 0][j * 16] = make_int4(0, 0, 0, 0);
  } else if (tid < 96) {
    int t3 = tid - 64;
    int node = t3 >> 4, s = t3 & 15;
    int slot = (s < 3) ? s : (256 + s);
    lds.xs16[node][slot] = (f16)0.f;
  }
  __syncthreads();

  // ---- L1 ----
  {
    const int cht = w & 1;
    const int o_lane = cht * 32 + (l & 31);
    const int khalf = l >> 5;
    const f16x8 w0frag = *(const f16x8*)&w0f[o_lane * 16 + khalf * 8];
    f32x16 binit;
#pragma unroll
    for (int g = 0; g < 4; g++) {
      const float4 b4 = *(const float4*)&cb0[cht * 32 + 8 * g + khalf * 4];
      binit[4 * g + 0] = b4.x; binit[4 * g + 1] = b4.y;
      binit[4 * g + 2] = b4.z; binit[4 * g + 3] = b4.w;
    }
    for (int mt = (w >> 1); mt < 8; mt += 2) {
      const int mo = mt * 32 + (l & 31);
      const int node = mo >> 7;
      const int po = mo & 127;
      union { uint u[4]; f16x8 v; } au;
      const char* ap = (const char*)&lds.xs16[node][2 * po + khalf * 8];
#pragma unroll
      for (int j = 0; j < 4; j++) au.u[j] = *(const uint*)(ap + 4 * j);
      f32x16 acc = __builtin_amdgcn_mfma_f32_32x32x16_f16(w0frag, au.v, binit, 0, 0, 0);
      const int orow = (po >> 1) + 1;
      const int ofx = orow & 7;
      char* base = (char*)lds.A.act1 + ((node * 2 + (po & 1)) * 66 + orow) * 128 + khalf * 8;
#pragma unroll
      for (int g = 0; g < 4; g++) {
        f16x4 h4;
        h4[0] = (f16)fmaxf(acc[4 * g + 0], 0.f);
        h4[1] = (f16)fmaxf(acc[4 * g + 1], 0.f);
        h4[2] = (f16)fmaxf(acc[4 * g + 2], 0.f);
        h4[3] = (f16)fmaxf(acc[4 * g + 3], 0.f);
        *(f16x4*)(base + (((cht * 4 + g) ^ ofx) << 4)) = h4;
      }
    }
  }
  __syncthreads();

  // ---- L2 -> LDS bounce -> coalesced a2g ----
  {
    const int cht = w & 1;
    const int o_lane = cht * 32 + (l & 31);
    const int khalf = l >> 5;
    f16x8 wf[5][4];
#pragma unroll
    for (int k = 0; k < 5; k++)
#pragma unroll
      for (int s = 0; s < 4; s++)
        wf[k][s] = *(const f16x8*)&wbmid[(k * 64 + o_lane) * 64 + s * 16 + khalf * 8];
    f32x16 binit;
#pragma unroll
    for (int g = 0; g < 4; g++) {
      const float4 b4 = *(const float4*)&cb_mid[cht * 32 + 8 * g + khalf * 4];
      binit[4 * g + 0] = b4.x; binit[4 * g + 1] = b4.y;
      binit[4 * g + 2] = b4.z; binit[4 * g + 3] = b4.w;
    }
    f16x4 outv[2][4];
#pragma unroll
    for (int it = 0; it < 2; it++) {
      const int mt = (w >> 1) + it * 2;
      const int mo = mt * 32 + (l & 31);
      const int node = mo >> 6;
      const int po = mo & 63;
      f32x16 acc = binit;
#pragma unroll
      for (int k = 0; k < 5; k++) {
        const int d = k - 2;
        const int par = d & 1;
        const int row = po + (d >> 1) + 1;
        const char* rb = (char*)lds.A.act1 + ((node * 2 + par) * 66 + row) * 128;
        const int fx = row & 7;
#pragma unroll
        for (int s = 0; s < 4; s++) {
          const int c8 = 2 * s + khalf;
          f16x8 af = *(const f16x8*)(rb + ((c8 ^ fx) << 4));
          acc = __builtin_amdgcn_mfma_f32_32x32x16_f16(wf[k][s], af, acc, 0, 0, 0);
        }
      }
#pragma unroll
      for (int g = 0; g < 4; g++) {
        outv[it][g][0] = (f16)fmaxf(acc[4 * g + 0], 0.f);
        outv[it][g][1] = (f16)fmaxf(acc[4 * g + 1], 0.f);
        outv[it][g][2] = (f16)fmaxf(acc[4 * g + 2], 0.f);
        outv[it][g][3] = (f16)fmaxf(acc[4 * g + 3], 0.f);
      }
    }
    __syncthreads();
#pragma unroll
    for (int it = 0; it < 2; it++) {
      const int mt = (w >> 1) + it * 2;
      const int row = mt * 32 + (l & 31);
      char* base = lds.A.a2s + row * 128 + khalf * 8;
#pragma unroll
      for (int g = 0; g < 4; g++)
        *(f16x4*)(base + (((cht * 4 + g) ^ (row & 7)) << 4)) = outv[it][g];
    }
    __syncthreads();
    char* gout = (char*)a2g + (size_t)n0 * 8192;
#pragma unroll
    for (int i = 0; i < 4; i++) {
      const int idx = tid + i * 256;
      const int row = idx >> 3, s = idx & 7;
      int4 v = *(const int4*)(lds.A.a2s + row * 128 + ((s ^ (row & 7)) << 4));
      *(int4*)(gout + idx * 16) = v;
    }
  }
}

// ---------------------------------------------------------------------------
// K_b: L3 + L4 + L5 + avg-pool + encoder — 4 nodes/block, LDS-aliased (R18).
// ---------------------------------------------------------------------------
struct alignas(16) L3LDS {
  union {
    char in2[4][2][34][128];       // 34816 (live: staging .. L3)
    struct {
      char act4[4][2][10][128];    // 10240 (live: L4 .. L5)
      float act5[32][68];          // 8704  (live: L5 .. pool)
      float pooled[4][256];        // 4096
      float encred[4][2][64];      // 2048
    } t;                            // 25088
  } U;
  char act3[4][2][18][128];        // 18432
};                                  // 53248 B -> 3 blocks/CU

__global__ __launch_bounds__(256, 3) void conv_l3tail_kernel(
    const f16* __restrict__ a2g,
    const f16* __restrict__ wbmid, const float* __restrict__ cb_mid,
    const f16* __restrict__ wb5, const float* __restrict__ cb_last,
    const f16* __restrict__ enc_w16, const float* __restrict__ enc_b,
    float* __restrict__ henc) {
  __shared__ L3LDS lds;
  const int tid = threadIdx.x;
  const int w = tid >> 6, l = tid & 63;
  const int n0 = blockIdx.x * 4;

#pragma unroll
  for (int i = 0; i < 8; i++) {
    const int idx = tid + i * 256;
    const int node = idx >> 9;
    const int rem = idx & 511;
    const int p = rem >> 3, s8 = rem & 7;
    const int row = (p >> 1) + 1, par = p & 1;
    int4 v = *(const int4*)&a2g[((size_t)(n0 + node) * 64 + p) * 64 + s8 * 8];
    *(int4*)((char*)lds.U.in2 + ((node * 2 + par) * 34 + row) * 128
             + ((s8 ^ (row & 7)) << 4)) = v;
  }
  for (int gg = tid; gg < 256; gg += 256) {
    int which = gg >> 7;
    int t = gg & 127;
    int node = t >> 5, tt = t & 31;
    int par = (tt >> 3) & 1, hi = tt >> 4, j = tt & 7;
    if (which == 0)
      *(int4*)&lds.U.in2[node][par][hi ? 33 : 0][j * 16] = make_int4(0, 0, 0, 0);
    else
      *(int4*)&lds.act3[node][par][hi ? 17 : 0][j * 16] = make_int4(0, 0, 0, 0);
  }
  __syncthreads();

  conv_mid<4, 5, 34, 18>(wbmid + 5 * 64 * 64, cb_mid + 64,
                         (char*)lds.U.in2, (char*)lds.act3, w, l);
  __syncthreads();

  if (tid < 128) {
    int node = tid >> 5, tt = tid & 31;
    int par = (tt >> 3) & 1, hi = tt >> 4, j = tt & 7;
    *(int4*)&lds.U.t.act4[node][par][hi ? 9 : 0][j * 16] = make_int4(0, 0, 0, 0);
  }
  conv_mid<2, 4, 18, 10>(wbmid + 2 * 5 * 64 * 64, cb_mid + 128,
                         (char*)lds.act3, (char*)lds.U.t.act4, w, l);
  __syncthreads();

  {
    const int ch_row = w * 16 + (l & 15);
    const int kq = l >> 4;
    f16x8 wf5[3][2];
#pragma unroll
    for (int k = 0; k < 3; k++)
#pragma unroll
      for (int s = 0; s < 2; s++)
        wf5[k][s] = *(const f16x8*)&wb5[(k * 64 + ch_row) * 64 + s * 32 + kq * 8];
    const float4 b4 = *(const float4*)&cb_last[w * 16 + kq * 4];
#pragma unroll
    for (int pt = 0; pt < 2; pt++) {
      f32x4 acc5 = {b4.x, b4.y, b4.z, b4.w};
      const int pos = pt * 16 + (l & 15);
      const int nd5 = pos >> 3, p5 = pos & 7;
#pragma unroll
      for (int k = 0; k < 3; k++) {
        const int d = k - 1;
        const int par = d & 1;
        const int row = p5 + (d >> 1) + 1;
        const char* rb = (char*)lds.U.t.act4 + ((nd5 * 2 + par) * 10 + row) * 128;
        const int fx = row & 7;
#pragma unroll
        for (int s = 0; s < 2; s++) {
          const int c8 = 4 * s + kq;
          f16x8 af = *(const f16x8*)(rb + ((c8 ^ fx) << 4));
          acc5 = __builtin_amdgcn_mfma_f32_16x16x32_f16(wf5[k][s], af, acc5, 0, 0, 0);
        }
      }
      f32x4 o4;
      o4[0] = fmaxf(acc5[0], 0.f);
      o4[1] = fmaxf(acc5[1], 0.f);
      o4[2] = fmaxf(acc5[2], 0.f);
      o4[3] = fmaxf(acc5[3], 0.f);
      *(f32x4*)&lds.U.t.act5[pos][w * 16 + kq * 4] = o4;
    }
  }
  __syncthreads();

  for (int jj = tid; jj < 1024; jj += 256) {
    int node = jj >> 8, j = jj & 255;
    int c = j >> 2, q = j & 3;
    const float* a5 = &lds.U.t.act5[node * 8][0];
    float v = a5[(2 * q) * 68 + c] + a5[(2 * q + 1) * 68 + c];
    if (q > 0) v += a5[(2 * q - 1) * 68 + c];
    lds.U.t.pooled[node][j] = v * (1.f / 3.f);
  }
  __syncthreads();

  for (int nn = 0; nn < 4; nn += 2) {
    const int node = nn + (tid >> 7);
    const int tt = tid & 127;
    const int o = tt & 63, jg = tt >> 6;
    float acc = 0.f;
    const f16x8* ew = (const f16x8*)&enc_w16[o * 256 + jg * 128];
    const float4* pj = (const float4*)&lds.U.t.pooled[node][jg * 128];
#pragma unroll 4
    for (int j8 = 0; j8 < 16; j8++) {
      f16x8 e8 = ew[j8];
      float4 p0 = pj[2 * j8], p1 = pj[2 * j8 + 1];
      acc += (float)e8[0] * p0.x + (float)e8[1] * p0.y +
             (float)e8[2] * p0.z + (float)e8[3] * p0.w +
             (float)e8[4] * p1.x + (float)e8[5] * p1.y +
             (float)e8[6] * p1.z + (float)e8[7] * p1.w;
    }
    lds.U.t.encred[node][jg][o] = acc;
  }
  __syncthreads();
  {
    int node = tid >> 6, o = tid & 63;
    henc[(size_t)(n0 + node) * 64 + o] =
        lds.U.t.encred[node][0][o] + lds.U.t.encred[node][1][o] + enc_b[o];
  }
}

// ---------------------------------------------------------------------------
// merged weight prep: conv f16 + enc f16 + GNN bf16 hi/lo
// ---------------------------------------------------------------------------
__global__ void wprep_all(const float* __restrict__ cw0,
                          const float* __restrict__ cw_mid, const float* __restrict__ cw_last,
                          const float* __restrict__ enc_w,
                          const float* __restrict__ g0_rel, const float* __restrict__ g0_root,
                          const float* __restrict__ g0_rel_b,
                          const float* __restrict__ g_rel, const float* __restrict__ g_root,
                          const float* __restrict__ g_rel_b,
                          f16* __restrict__ w0f, f16* __restrict__ wbmid, f16* __restrict__ wb5,
                          f16* __restrict__ enc_w16,
                          bf16* __restrict__ wg, float* __restrict__ bg) {
  int idx = blockIdx.x * 256 + threadIdx.x;
  if (idx < 64 * 16) {
    int o = idx >> 4, k = idx & 15;
    w0f[idx] = (k < 7) ? (f16)cw0[o * 7 + k] : (f16)0.f;
  }
  if (idx < 3 * 5 * 64 * 64) {
    int lay = idx / (5 * 64 * 64);
    int rem = idx % (5 * 64 * 64);
    int k = rem / 4096;
    int o = (rem >> 6) & 63;
    int c = rem & 63;
    wbmid[idx] = (f16)cw_mid[((lay * 64 + o) * 64 + c) * 5 + k];
  } else {
    int i2 = idx - 3 * 5 * 64 * 64;
    if (i2 < 3 * 64 * 64) {
      int k = i2 / 4096;
      int o = (i2 >> 6) & 63;
      int c = i2 & 63;
      wb5[i2] = (f16)cw_last[(o * 64 + c) * 3 + k];
    }
  }
  if (idx < 64 * 256) enc_w16[idx] = (f16)enc_w[idx];
  if (idx < 128 * 128) {
    int o = idx >> 7, k = idx & 127;
    float v = (k < 64) ? g0_rel[o * 64 + k] : g0_root[o * 64 + (k - 64)];
    bf16 h = (bf16)v;
    wg[idx] = h;
    wg[128 * 128 + idx] = (bf16)(v - (float)h);
  }
  if (idx < 7 * 128 * 256) {
    int lsel = idx / (128 * 256);
    int r = idx % (128 * 256);
    int o = r >> 8, k = r & 255;
    float v = (k < 128) ? g_rel[(lsel * 128 + o) * 128 + k]
                        : g_root[(lsel * 128 + o) * 128 + (k - 128)];
    bf16 h = (bf16)v;
    size_t base = 2 * 128 * 128 + (size_t)lsel * 2 * 128 * 256;
    wg[base + r] = h;
    wg[base + 128 * 256 + r] = (bf16)(v - (float)h);
  }
  if (idx < 8 * 128) {
    int lsel = idx >> 7, o = idx & 127;
    bg[idx] = (lsel == 0) ? g0_rel_b[o] : g_rel_b[(lsel - 1) * 128 + o];
  }
}

// ---------------------------------------------------------------------------
// CSR build
// ---------------------------------------------------------------------------
__global__ void hist_kernel(const int* __restrict__ dst, int* __restrict__ cnt) {
  int e = blockIdx.x * 256 + threadIdx.x;
  atomicAdd(&cnt[dst[e]], 1);
}

__global__ void scan_kernel(const int* __restrict__ cnt, int* __restrict__ rp) {
  __shared__ int part[256];
  int t = threadIdx.x;
  int base = t * 32;
  int local[32];
  int s = 0;
#pragma unroll
  for (int i = 0; i < 32; i++) { local[i] = cnt[base + i]; s += local[i]; }
  part[t] = s;
  __syncthreads();
  for (int off = 1; off < 256; off <<= 1) {
    int v = (t >= off) ? part[t - off] : 0;
    __syncthreads();
    part[t] += v;
    __syncthreads();
  }
  int run = part[t] - s;
#pragma unroll
  for (int i = 0; i < 32; i++) { rp[base + i] = run; run += local[i]; }
  if (t == 255) rp[N_NODES] = run;
}

__global__ void fill_kernel(const int* __restrict__ src, const int* __restrict__ dst,
                            const int* __restrict__ rp, int* __restrict__ cur,
                            int* __restrict__ csr) {
  int e = blockIdx.x * 256 + threadIdx.x;
  int r = dst[e];
  int p = atomicAdd(&cur[r], 1);
  csr[rp[r] + p] = src[e];
}

// ---------------------------------------------------------------------------
// f32 gather, split neighbor list across 2 lane-groups (halved latency
// chain), 4-deep float4 body per group, combine via shfl_xor(LPN).
// D=128: 64 lanes/node (4 nodes/block); D=64: 32 lanes/node (8 nodes/block).
// ---------------------------------------------------------------------------
template<int D>
__global__ __launch_bounds__(256) void gatherf(
    const float* __restrict__ h, const int* __restrict__ csr,
    const int* __restrict__ rp, float* __restrict__ agg) {
  constexpr int LPN = D / 4;                  // lanes per group
  const int node = blockIdx.x * (128 / LPN) + (threadIdx.x / (2 * LPN));
  const int grp = (threadIdx.x / LPN) & 1;
  const int cl = threadIdx.x & (LPN - 1);
  const int s = rp[node], e = rp[node + 1];
  float4 a0 = make_float4(0.f, 0.f, 0.f, 0.f);
  float4 a1 = make_float4(0.f, 0.f, 0.f, 0.f);
  float4 a2 = make_float4(0.f, 0.f, 0.f, 0.f);
  float4 a3 = make_float4(0.f, 0.f, 0.f, 0.f);
  int i = s + grp;                            // this group's interleaved list
  for (; i + 6 < e; i += 8) {
    const int m0 = csr[i], m1 = csr[i + 2], m2 = csr[i + 4], m3 = csr[i + 6];
    float4 v0 = *(const float4*)&h[(size_t)m0 * D + cl * 4];
    float4 v1 = *(const float4*)&h[(size_t)m1 * D + cl * 4];
    float4 v2 = *(const float4*)&h[(size_t)m2 * D + cl * 4];
    float4 v3 = *(const float4*)&h[(size_t)m3 * D + cl * 4];
    a0.x += v0.x; a0.y += v0.y; a0.z += v0.z; a0.w += v0.w;
    a1.x += v1.x; a1.y += v1.y; a1.z += v1.z; a1.w += v1.w;
    a2.x += v2.x; a2.y += v2.y; a2.z += v2.z; a2.w += v2.w;
    a3.x += v3.x; a3.y += v3.y; a3.z += v3.z; a3.w += v3.w;
  }
  for (; i < e; i += 2) {
    const int m0 = csr[i];
    float4 v0 = *(const float4*)&h[(size_t)m0 * D + cl * 4];
    a0.x += v0.x; a0.y += v0.y; a0.z += v0.z; a0.w += v0.w;
  }
  float4 r0;
  r0.x = (a0.x + a1.x) + (a2.x + a3.x);
  r0.y = (a0.y + a1.y) + (a2.y + a3.y);
  r0.z = (a0.z + a1.z) + (a2.z + a3.z);
  r0.w = (a0.w + a1.w) + (a2.w + a3.w);
  // combine the two groups' partials (lanes cl and cl+LPN hold same channels)
  r0.x += __shfl_xor(r0.x, LPN);
  r0.y += __shfl_xor(r0.y, LPN);
  r0.z += __shfl_xor(r0.z, LPN);
  r0.w += __shfl_xor(r0.w, LPN);
  if (grp == 0)
    *(float4*)&agg[(size_t)node * D + cl * 4] = r0;
}

// ---------------------------------------------------------------------------
// GNN layer GEMM, bf16 hi/lo split both operands. 32 nodes/block. (R12)
// ---------------------------------------------------------------------------
template<int K>
__global__ __launch_bounds__(256) void gnn_gemm_bf(
    const float* __restrict__ agg, const float* __restrict__ hroot,
    const bf16* __restrict__ wg, const float* __restrict__ bg,
    float* __restrict__ hout) {
  constexpr int F = K / 2;
  constexpr int ROWB = K * 2;
  constexpr int KSTEPS = K / 16;
  __shared__ alignas(16) char smem[2][32 * K * 2];
  const int tid = threadIdx.x;
  const int l = tid & 63, w = tid >> 6;
  const int n0 = blockIdx.x * 32;

  {
    const int row = tid >> 3, p = tid & 7;
    constexpr int cpp = K / 64;
#pragma unroll
    for (int j = 0; j < cpp; j++) {
      const int slot = p * cpp + j;
      const int c0 = slot * 8;
      const float* src = (c0 < F) ? &agg[(size_t)(n0 + row) * F + c0]
                                  : &hroot[(size_t)(n0 + row) * F + (c0 - F)];
      float4 v0 = ((const float4*)src)[0];
      float4 v1 = ((const float4*)src)[1];
      float vv[8] = {v0.x, v0.y, v0.z, v0.w, v1.x, v1.y, v1.z, v1.w};
      bf16x8 hi8, lo8;
#pragma unroll
      for (int e = 0; e < 8; e++) {
        float v = vv[e];
        bf16 h = (bf16)v;
        hi8[e] = h;
        lo8[e] = (bf16)(v - (float)h);
      }
      const int off = row * ROWB + ((slot ^ (row & 7)) << 4);
      *(bf16x8*)(smem[0] + off) = hi8;
      *(bf16x8*)(smem[1] + off) = lo8;
    }
  }

  const int ch = w * 32 + (l & 31);
  const int khalf = l >> 5;
  bf16x8 whi[KSTEPS], wlo[KSTEPS];
  const bf16* wrow = wg + (size_t)ch * K + khalf * 8;
#pragma unroll
  for (int ks = 0; ks < KSTEPS; ks++) {
    whi[ks] = *(const bf16x8*)&wrow[ks * 16];
    wlo[ks] = *(const bf16x8*)&wrow[128 * K + ks * 16];
  }
  const float bv = bg[ch];

  __syncthreads();

  const int row0 = l & 31;
  f32x16 acc = {0,0,0,0,0,0,0,0,0,0,0,0,0,0,0,0};
#pragma unroll
  for (int ks = 0; ks < KSTEPS; ks++) {
    const int slot = ks * 2 + khalf;
    const int off = row0 * ROWB + ((slot ^ (row0 & 7)) << 4);
    bf16x8 ah = *(const bf16x8*)(smem[0] + off);
    bf16x8 al = *(const bf16x8*)(smem[1] + off);
    acc = __builtin_amdgcn_mfma_f32_32x32x16_bf16(ah, whi[ks], acc, 0, 0, 0);
    acc = __builtin_amdgcn_mfma_f32_32x32x16_bf16(al, whi[ks], acc, 0, 0, 0);
    acc = __builtin_amdgcn_mfma_f32_32x32x16_bf16(ah, wlo[ks], acc, 0, 0, 0);
  }

#pragma unroll
  for (int r = 0; r < 16; r++) {
    const int nl = (r & 3) + 8 * (r >> 2) + 4 * khalf;
    hout[(size_t)(n0 + nl) * 128 + ch] = fmaxf(acc[r] + bv, 0.f);
  }
}

// ---------------------------------------------------------------------------
// graph mean-pool (block per graph, no atomics) + MLP head
// ---------------------------------------------------------------------------
__global__ __launch_bounds__(256) void poolg(const float* __restrict__ h,
                                             float* __restrict__ pooled) {
  const int g = blockIdx.x;
  const int tid = threadIdx.x;
  const int ch = tid & 127, half = tid >> 7;
  const float* base = h + ((size_t)g * 64 + half * 32) * 128 + ch;
  float s = 0.f;
#pragma unroll 8
  for (int i = 0; i < 32; i++) s += base[(size_t)i * 128];
  __shared__ float red[256];
  red[tid] = s;
  __syncthreads();
  if (tid < 128) pooled[(size_t)g * 128 + tid] = (red[tid] + red[tid + 128]) * (1.f / 64.f);
}

__global__ __launch_bounds__(128) void mlp_kernel(
    const float* __restrict__ pooled,
    const float* __restrict__ lin_w, const float* __restrict__ lin_b,
    const float* __restrict__ out_w, const float* __restrict__ out_b,
    float* __restrict__ out) {
  const int g = blockIdx.x;
  const int t = threadIdx.x;
  __shared__ float hs[128];
  __shared__ float lg[2];
  hs[t] = pooled[(size_t)g * 128 + t];
  __syncthreads();
  for (int lsel = 0; lsel < 3; lsel++) {
    float acc = lin_b[lsel * 128 + t];
    for (int j = 0; j < 128; j++) acc += hs[j] * lin_w[(lsel * 128 + t) * 128 + j];
    __syncthreads();
    hs[t] = fmaxf(acc, 0.f);
    __syncthreads();
  }
  if (t < 2) {
    float acc = out_b[t];
    for (int j = 0; j < 128; j++) acc += hs[j] * out_w[t * 128 + j];
    lg[t] = acc;
  }
  __syncthreads();
  if (t < 2) {
    float m = fmaxf(lg[0], lg[1]);
    float lse = m + logf(expf(lg[0] - m) + expf(lg[1] - m));
    out[g * 2 + t] = lg[t] - lse;
  }
}

// ---------------------------------------------------------------------------
extern "C" void kernel_launch(void* const* d_in, const int* in_sizes, int n_in,
                              void* d_out, int out_size, void* d_ws, size_t ws_size,
                              hipStream_t stream) {
  const float* x       = (const float*)d_in[0];
  const int*   edge    = (const int*)d_in[1];
  const float* cw0     = (const float*)d_in[3];
  const float* cb0     = (const float*)d_in[4];
  const float* cw_mid  = (const float*)d_in[5];
  const float* cb_mid  = (const float*)d_in[6];
  const float* cw_last = (const float*)d_in[7];
  const float* cb_last = (const float*)d_in[8];
  const float* enc_w   = (const float*)d_in[9];
  const float* enc_b   = (const float*)d_in[10];
  const float* g0_rel_w  = (const float*)d_in[11];
  const float* g0_rel_b  = (const float*)d_in[12];
  const float* g0_root_w = (const float*)d_in[13];
  const float* g_rel_w   = (const float*)d_in[14];
  const float* g_rel_b   = (const float*)d_in[15];
  const float* g_root_w  = (const float*)d_in[16];
  const float* lin_w     = (const float*)d_in[17];
  const float* lin_b     = (const float*)d_in[18];
  const float* out_w     = (const float*)d_in[19];
  const float* out_b     = (const float*)d_in[20];
  float* out = (float*)d_out;

  const int* esrc = edge;
  const int* edst = edge + E_EDGES;

  char* ws = (char*)d_ws;
  size_t off = 0;
  auto alloc = [&](size_t bytes) {
    void* p = ws + off;
    off += (bytes + 255) & ~size_t(255);
    return p;
  };
  float* henc = (float*)alloc((size_t)N_NODES * 64 * 4);
  float* hA   = (float*)alloc((size_t)N_NODES * 128 * 4);
  float* hB   = (float*)alloc((size_t)N_NODES * 128 * 4);
  float* agg  = (float*)alloc((size_t)N_NODES * 128 * 4);
  bf16* wg    = (bf16*)alloc((size_t)(128 * 128 + 7 * 128 * 256) * 2 * 2);
  float* bg   = (float*)alloc((size_t)8 * 128 * 4);
  float* pooled = (float*)alloc((size_t)G * 128 * 4);
  int* cnt  = (int*)alloc((size_t)N_NODES * 4);
  int* rp   = (int*)alloc((size_t)(N_NODES + 1) * 4);
  int* cur  = (int*)alloc((size_t)N_NODES * 4);
  int* csr  = (int*)alloc((size_t)E_EDGES * 4);
  f16* w0f   = (f16*)alloc((size_t)64 * 16 * 2);
  f16* wbmid = (f16*)alloc((size_t)3 * 5 * 64 * 64 * 2);
  f16* wb5   = (f16*)alloc((size_t)3 * 64 * 64 * 2);
  f16* enc_w16 = (f16*)alloc((size_t)64 * 256 * 2);
  f16* a2g   = (f16*)alloc((size_t)N_NODES * 64 * 64 * 2);   // 67 MB

  hipMemsetAsync(cnt, 0, (size_t)N_NODES * 4, stream);
  hipMemsetAsync(cur, 0, (size_t)N_NODES * 4, stream);

  wprep_all<<<896, 256, 0, stream>>>(cw0, cw_mid, cw_last, enc_w,
                                     g0_rel_w, g0_root_w, g0_rel_b,
                                     g_rel_w, g_root_w, g_rel_b,
                                     w0f, wbmid, wb5, enc_w16, wg, bg);
  conv_l1l2_kernel<<<N_NODES / 2, 256, 0, stream>>>(x, w0f, cb0, wbmid, cb_mid, a2g);
  conv_l3tail_kernel<<<N_NODES / 4, 256, 0, stream>>>(
      a2g, wbmid, cb_mid, wb5, cb_last, enc_w16, enc_b, henc);

  hist_kernel<<<E_EDGES / 256, 256, 0, stream>>>(edst, cnt);
  scan_kernel<<<1, 256, 0, stream>>>(cnt, rp);
  fill_kernel<<<E_EDGES / 256, 256, 0, stream>>>(esrc, edst, rp, cur, csr);

  // layer 0 (K=128: 64 agg + 64 root); D=64 -> 32 lanes/node, 8 nodes/block
  gatherf<64><<<N_NODES / 8, 256, 0, stream>>>(henc, csr, rp, agg);
  gnn_gemm_bf<128><<<N_NODES / 32, 256, 0, stream>>>(agg, henc, wg, bg, hA);

  float* hprev = hA;
  float* hnext = hB;
  for (int lsel = 0; lsel < 7; lsel++) {
    // D=128 -> 64 lanes/node, 4 nodes/block
    gatherf<128><<<N_NODES / 4, 256, 0, stream>>>(hprev, csr, rp, agg);
    gnn_gemm_bf<256><<<N_NODES / 32, 256, 0, stream>>>(
        agg, hprev, wg + 2 * 128 * 128 + (size_t)lsel * 2 * 128 * 256,
        bg + (lsel + 1) * 128, hnext);
    float* tmp = hprev; hprev = hnext; hnext = tmp;
  }

  poolg<<<G, 256, 0, stream>>>(hprev, pooled);
  mlp_kernel<<<G, 128, 0, stream>>>(pooled, lin_w, lin_b, out_w, out_b, out);
}